// Round 5
// baseline (87.383 us; speedup 1.0000x reference)
//
#include <hip/hip_runtime.h>

// out[(i*7+k)*C + c] = bias[(i*7+k)*C + c] + sum_j x[c*49 + j*7 + i] * weight[(j*7+k)*C + c]
//
// Memory-bound fp32, ~402 MB logical traffic. R4 = 73 us @ 5.5 TB/s logical,
// but HBM counters (FETCH 150 MB, L3-resident inputs) show only 3.5 TB/s of
// HBM => latency-limited, not BW-limited. This version raises occupancy from
// 21 to 28 waves/CU by splitting the i-range across threadIdx.z (896-thread
// blocks, 14 waves, 2 blocks/CU at 50 KiB LDS). w loads duplicate 2x per
// block (L1 hits only). b loads are batched ahead of LDS reads for MLP.
//
// Layout recap: thread (q,k,ih) owns channels cbase+4q..+3 for one k and
// i in {0..3} (ih=0) or {4..6} (ih=1). w/b/out accessed as float4 (16B/lane,
// coalesced). x staged transposed in LDS with XOR swizzle g=(pos>>2)&7 so
// both the transpose scatter-write and the row-broadcast f4 reads are
// conflict-light. out uses nontemporal stores (write-once stream).

typedef float f4 __attribute__((ext_vector_type(4)));

constexpr int C    = 524288;
constexpr int HW   = 49;
constexpr int CHB  = 256;              // channels per block
constexpr int NTHR = 64 * 7 * 2;       // 896 threads = 14 waves
constexpr int RS   = CHB;              // LDS row stride (dwords) per pos
constexpr int NF4  = CHB * HW / 4;     // 3136 float4 per block slab

template<int IBEG, int IEND>
__device__ __forceinline__ void do_is(const float* __restrict__ xs, const f4* wq,
                                      const float* __restrict__ b, float* __restrict__ out,
                                      int q, int kk, int c) {
    // batch bias loads first: deepens outstanding global loads
    f4 bacc[IEND - IBEG];
#pragma unroll
    for (int i = IBEG; i < IEND; ++i)
        bacc[i - IBEG] = *reinterpret_cast<const f4*>(b + (size_t)(i * 7 + kk) * C + c);

#pragma unroll
    for (int i = IBEG; i < IEND; ++i) {
        f4 xv[7];
#pragma unroll
        for (int j = 0; j < 7; ++j) {
            const int pos = j * 7 + i;
            const int g   = (pos >> 2) & 7;
            xv[j] = *reinterpret_cast<const f4*>(xs + pos * RS + ((q ^ g) << 2));
        }
        f4 acc = bacc[i - IBEG];
#pragma unroll
        for (int j = 0; j < 7; ++j) {
            acc.x = fmaf(xv[j].x, wq[j].x, acc.x);
            acc.y = fmaf(xv[j].y, wq[j].y, acc.y);
            acc.z = fmaf(xv[j].z, wq[j].z, acc.z);
            acc.w = fmaf(xv[j].w, wq[j].w, acc.w);
        }
        __builtin_nontemporal_store(acc,
            reinterpret_cast<f4*>(out + (size_t)(i * 7 + kk) * C + c));
    }
}

__global__ __launch_bounds__(NTHR)
void mylinear_kernel(const float* __restrict__ x,
                     const float* __restrict__ w,
                     const float* __restrict__ b,
                     float* __restrict__ out) {
    __shared__ float xs[HW * CHB];     // 50176 B

    const int tid   = (threadIdx.z * 7 + threadIdx.y) * 64 + threadIdx.x;
    const int cbase = blockIdx.x * CHB;

    // ---- stage x slab, transposing channel-major -> pos-major with XOR swizzle ----
    const f4* __restrict__ xsrc = reinterpret_cast<const f4*>(x + (size_t)cbase * HW);
#pragma unroll
    for (int it = 0; it < (NF4 + NTHR - 1) / NTHR; ++it) {   // 4 iters, last partial
        const int idx = it * NTHR + tid;
        if (idx < NF4) {
            const f4 v = xsrc[idx];
#pragma unroll
            for (int t = 0; t < 4; ++t) {
                const int e   = idx * 4 + t;
                const int cl  = e / HW;            // local channel 0..255
                const int pos = e % HW;            // 0..48
                const int g   = (pos >> 2) & 7;
                const int sl  = (cl >> 2) ^ g;     // swizzled float4 slot
                xs[pos * RS + (sl << 2 | (cl & 3))] = v[t];
            }
        }
    }
    __syncthreads();

    // ---- compute ----
    const int q  = threadIdx.x;                // quad 0..63
    const int kk = threadIdx.y;                // 0..6
    const int c  = cbase + (q << 2);

    f4 wq[7];
#pragma unroll
    for (int j = 0; j < 7; ++j)
        wq[j] = *reinterpret_cast<const f4*>(w + (size_t)(j * 7 + kk) * C + c);

    if (threadIdx.z == 0) do_is<0, 4>(xs, wq, b, out, q, kk, c);
    else                  do_is<4, 7>(xs, wq, b, out, q, kk, c);
}

extern "C" void kernel_launch(void* const* d_in, const int* in_sizes, int n_in,
                              void* d_out, int out_size, void* d_ws, size_t ws_size,
                              hipStream_t stream) {
    const float* x = (const float*)d_in[0];
    const float* w = (const float*)d_in[1];
    const float* b = (const float*)d_in[2];
    float* out     = (float*)d_out;

    dim3 grid(C / CHB), block(64, 7, 2);
    mylinear_kernel<<<grid, block, 0, stream>>>(x, w, b, out);
}